// Round 20
// baseline (620.386 us; speedup 1.0000x reference)
//
#include <hip/hip_runtime.h>
#include <hip/hip_fp16.h>

#define N_NODES 100000
#define N_EDGES 800000
#define SLOT_CAP 64

typedef float4 f4;
typedef _Float16 half8 __attribute__((ext_vector_type(8)));
typedef float f32x4 __attribute__((ext_vector_type(4)));

__device__ __forceinline__ float lrelu(float x) { return x > 0.f ? x : 0.01f * x; }

__device__ __forceinline__ float2 h2f2(unsigned u) {
    union { unsigned w; __half2 h; } cv; cv.w = u;
    return __half22float2(cv.h);
}
__device__ __forceinline__ unsigned f2h2(float lo, float hi) {
    union { unsigned w; __half2 h; } cv; cv.h = __floats2half2_rn(lo, hi);
    return cv.w;
}

// ---------------- K0: pack all four weight matrices into MFMA b-frag layout (f16) -------
__global__ __launch_bounds__(256) void k0_pack(
    const float* __restrict__ uW1, const float* __restrict__ uW2,
    const float* __restrict__ mW1, const float* __restrict__ mW2,
    _Float16* __restrict__ W1p, _Float16* __restrict__ W2p,
    _Float16* __restrict__ W1e, _Float16* __restrict__ W2e)
{
    int t = blockIdx.x * 256 + threadIdx.x;   // 236*256 = 60416 slots total
    const float* W; _Float16* P; int s, KC, ldk;
    if (t < 51200)      { W = uW1; P = W1p; s = t;         KC = 20; ldk = 640; }
    else if (t < 56320) { W = uW2; P = W2p; s = t - 51200; KC = 20; ldk = 640; }
    else if (t < 58368) { W = mW1; P = W1e; s = t - 56320; KC = 4;  ldk = 128; }
    else                { W = mW2; P = W2e; s = t - 58368; KC = 4;  ldk = 128; }
    int nf = s / (KC * 64), r1 = s % (KC * 64), kc = r1 >> 6, l = r1 & 63;
    int row = nf * 16 + (l & 15);
    int k0 = kc * 32 + (l >> 4) * 8;
    const float* sp = W + (size_t)row * ldk + k0;
    _Float16 h[8];
#pragma unroll
    for (int i = 0; i < 8; ++i) h[i] = (_Float16)sp[i];
    *(uint4*)(P + (size_t)s * 8) = *(uint4*)h;
}

// ---------------- K_xt: convert x_t AND x_s (f32) -> fp16 (L2-friendly) ----------------
__global__ __launch_bounds__(256) void k_xt(
    const float* __restrict__ x_t, _Float16* __restrict__ x_t16,
    const float* __restrict__ x_s, _Float16* __restrict__ x_s16)
{
    int i = blockIdx.x * 256 + threadIdx.x;    // 3.2M threads: 1.6M x_t + 1.6M x_s
    const float* src; _Float16* dst; int g;
    if (i < 1600000) { src = x_t; dst = x_t16; g = i; }
    else             { src = x_s; dst = x_s16; g = i - 1600000; }
    f4 v = ((const f4*)src)[g];
    _Float16 h[4] = {(_Float16)v.x, (_Float16)v.y, (_Float16)v.z, (_Float16)v.w};
    *(uint2*)(dst + (size_t)g * 4) = *(uint2*)h;
}

// ---------------- K_slot: per-node edge-list build (atomics isolated) ------------------
__global__ __launch_bounds__(256) void k_slot(
    const int* __restrict__ src, int* __restrict__ cur, int* __restrict__ slot)
{
    int e = blockIdx.x * 256 + threadIdx.x;   // exactly N_EDGES
    int s = src[e];
    int pos = atomicAdd(&cur[s], 1);
    if (pos < SLOT_CAP) slot[s * SLOT_CAP + pos] = e;
}

// ---------------- K1: edge MLP (128->128->128) via f16 MFMA, W staged in LDS ----------
__global__ __launch_bounds__(512) void k1_mfma(
    const _Float16* __restrict__ x_t16, const float* __restrict__ ea,
    const _Float16* __restrict__ W1e, const float* __restrict__ mb1,
    const _Float16* __restrict__ W2e, const float* __restrict__ mb2,
    const int* __restrict__ tgt, unsigned short* __restrict__ msg)
{
    __shared__ _Float16 T[128 * 136];      // 34,816 B
    __shared__ _Float16 Wl[16384];         // 32,768 B
    const int tid = threadIdx.x;
    const int wid = tid >> 6, l = tid & 63;
    const int lr = l & 15, lq = l >> 4;
    const int e0 = blockIdx.x * 128;

    {
        const uint4* xt16 = (const uint4*)x_t16;
        const f4* ea4 = (const f4*)ea;
#pragma unroll
        for (int i = 0; i < 6; ++i) {
            int idx = tid + i * 512;           // 3072 groups: 1024 x_t16 + 2048 ea
            if (idx < 1024) {
                int e = idx >> 3, c8 = idx & 7;
                int tg = tgt[e0 + e];
                uint4 v = xt16[(size_t)tg * 8 + c8];
                *(uint4*)&T[e * 136 + c8 * 8] = v;
            } else {
                int j = idx - 1024;
                int e = j >> 4, c4 = j & 15;
                f4 v = ea4[(size_t)(e0 + e) * 16 + c4];
                _Float16 h[4] = {(_Float16)v.x, (_Float16)v.y, (_Float16)v.z, (_Float16)v.w};
                *(uint2*)&T[e * 136 + 64 + c4 * 4] = *(uint2*)h;
            }
        }
#pragma unroll
        for (int i = 0; i < 4; ++i) {
            int idx = tid + i * 512;           // 2048 uint4 = 32 KB
            ((uint4*)Wl)[idx] = ((const uint4*)W1e)[idx];
        }
    }
    __syncthreads();

    f32x4 acc[8];
#pragma unroll
    for (int nf = 0; nf < 8; ++nf) acc[nf] = (f32x4){0.f, 0.f, 0.f, 0.f};

    for (int kc = 0; kc < 4; ++kc) {
        half8 a = *(const half8*)&T[(wid * 16 + lr) * 136 + kc * 32 + lq * 8];
#pragma unroll
        for (int nf = 0; nf < 8; ++nf) {
            half8 b = *(const half8*)&Wl[((nf * 4 + kc) * 64 + l) * 8];
            acc[nf] = __builtin_amdgcn_mfma_f32_16x16x32_f16(a, b, acc[nf], 0, 0, 0);
        }
    }

#pragma unroll
    for (int nf = 0; nf < 8; ++nf) {
        float b1 = mb1[nf * 16 + lr];
#pragma unroll
        for (int i = 0; i < 4; ++i) {
            int row = wid * 16 + lq * 4 + i;
            T[row * 136 + nf * 16 + lr] = (_Float16)lrelu(acc[nf][i] + b1);
        }
    }
    __syncthreads();

#pragma unroll
    for (int i = 0; i < 4; ++i) {
        int idx = tid + i * 512;
        ((uint4*)Wl)[idx] = ((const uint4*)W2e)[idx];
    }
    __syncthreads();

#pragma unroll
    for (int nf = 0; nf < 8; ++nf) acc[nf] = (f32x4){0.f, 0.f, 0.f, 0.f};

    for (int kc = 0; kc < 4; ++kc) {
        half8 a = *(const half8*)&T[(wid * 16 + lr) * 136 + kc * 32 + lq * 8];
#pragma unroll
        for (int nf = 0; nf < 8; ++nf) {
            half8 b = *(const half8*)&Wl[((nf * 4 + kc) * 64 + l) * 8];
            acc[nf] = __builtin_amdgcn_mfma_f32_16x16x32_f16(a, b, acc[nf], 0, 0, 0);
        }
    }

#pragma unroll
    for (int nf = 0; nf < 8; ++nf) {
        float b2 = mb2[nf * 16 + lr];
#pragma unroll
        for (int i = 0; i < 4; ++i) {
            int row = wid * 16 + lq * 4 + i;
            T[row * 136 + nf * 16 + lr] = (_Float16)(acc[nf][i] + b2);
        }
    }
    __syncthreads();

#pragma unroll
    for (int i = 0; i < 4; ++i) {
        int idx = tid + i * 512;
        int row = idx >> 4, g = idx & 15;
        uint4 v = *(const uint4*)&T[row * 136 + g * 8];
        ((uint4*)(msg + (size_t)(e0 + row) * 128))[g] = v;
    }
}

// ---------------- K2: gather aggregation, one wave per node ----------------
__global__ __launch_bounds__(256) void k_agg(
    const int* __restrict__ cur, const int* __restrict__ slot,
    const unsigned short* __restrict__ msg,
    unsigned short* __restrict__ MU, unsigned short* __restrict__ SD,
    unsigned short* __restrict__ SK, unsigned short* __restrict__ KU)
{
    const int n = (blockIdx.x * 256 + threadIdx.x) >> 6;
    const int lane = threadIdx.x & 63;
    const int deg = cur[n];
    const int m = min(deg, SLOT_CAP);
    const unsigned* msg2 = (const unsigned*)msg;
    const int sl = slot[(size_t)n * SLOT_CAP + lane];

    unsigned uc[16];
    float s1a = 0.f, s1b = 0.f, s2a = 0.f, s2b = 0.f;
#pragma unroll
    for (int i = 0; i < 16; ++i) {
        if (i < m) {
            int e = __shfl(sl, i);
            unsigned u = msg2[(size_t)e * 64 + lane];
            uc[i] = u;
            float2 f = h2f2(u);
            s1a += f.x; s2a += f.x * f.x; s1b += f.y; s2b += f.y * f.y;
        }
    }
    for (int i = 16; i < m; ++i) {
        int e = __shfl(sl, i);
        float2 f = h2f2(msg2[(size_t)e * 64 + lane]);
        s1a += f.x; s2a += f.x * f.x; s1b += f.y; s2b += f.y * f.y;
    }

    float inv = 1.f / fmaxf((float)deg, 1.f);
    float mua = s1a * inv, mub = s1b * inv;
    float vra = s2a * inv - mua * mua; vra = vra > 0.f ? vra : 0.01f * vra;
    float vrb = s2b * inv - mub * mub; vrb = vrb > 0.f ? vrb : 0.01f * vrb;
    float sda = sqrtf(vra + 1e-6f), sdb = sqrtf(vrb + 1e-6f);

    float c3a = 0.f, c4a = 0.f, c3b = 0.f, c4b = 0.f;
#pragma unroll
    for (int i = 0; i < 16; ++i) {
        if (i < m) {
            float2 f = h2f2(uc[i]);
            float ca = f.x - mua, cb = f.y - mub;
            float c2a = ca * ca, c2b = cb * cb;
            c3a += c2a * ca; c4a += c2a * c2a; c3b += c2b * cb; c4b += c2b * c2b;
        }
    }
    for (int i = 16; i < m; ++i) {
        int e = __shfl(sl, i);
        float2 f = h2f2(msg2[(size_t)e * 64 + lane]);
        float ca = f.x - mua, cb = f.y - mub;
        float c2a = ca * ca, c2b = cb * cb;
        c3a += c2a * ca; c4a += c2a * c2a; c3b += c2b * cb; c4b += c2b * c2b;
    }

    float ska = c3a * inv / (sda * sda * sda);
    float skb = c3b * inv / (sdb * sdb * sdb);
    float p;
    p = sda * sda; float kua = c4a * inv / (p * p);
    p = sdb * sdb; float kub = c4b * inv / (p * p);

    size_t o = (size_t)n * 64 + lane;
    ((unsigned*)MU)[o] = f2h2(mua, mub);
    ((unsigned*)SD)[o] = f2h2(sda, sdb);
    ((unsigned*)SK)[o] = f2h2(ska, skb);
    ((unsigned*)KU)[o] = f2h2(kua, kub);
}

// ---------------- K3 v6: 128 nodes/block, K-split Hl, 8:1 MFMA:b + double-buffered b ---
// r19 PMC: k3=195us, MFMA floor 36us; binding term = per-kc b-load chain (5 loads per
// 25 MFMA, no prefetch). Now: wave owns 8mf x 5nf (40 MFMA : 5 b-loads), b-frags for
// kc+1 preloaded into bfn[] during current MFMAs (static unroll). Hl K-split [128][328]
// (84KB): stage K-half, compute 10 kc, restage. Layer2 in two halves w/ h1 writeback.
// W1p traffic 1.02GB -> 640MB. Regs ~240 (acc 160 AGPR), capped by (512,2).
__global__ __launch_bounds__(512, 2) void k3_mfma(
    const _Float16* __restrict__ x_s16, const float* __restrict__ x_u,
    const unsigned short* __restrict__ MU, const unsigned short* __restrict__ SD,
    const unsigned short* __restrict__ SK, const unsigned short* __restrict__ KU,
    const _Float16* __restrict__ W1p, const float* __restrict__ ub1,
    const _Float16* __restrict__ W2p, const float* __restrict__ ub2,
    float* __restrict__ hout, float* __restrict__ bn_acc)
{
    __shared__ _Float16 Hl[128 * 328];    // 83,968 B
    const int tid = threadIdx.x;
    const int wid = tid >> 6, l = tid & 63;
    const int lr = l & 15, lq = l >> 4;
    const int n0 = blockIdx.x * 128;

    const uint4* xs16 = (const uint4*)x_s16;
    const uint4* st4[4] = {(const uint4*)MU, (const uint4*)SD,
                           (const uint4*)SK, (const uint4*)KU};

    f32x4 acc[8][5];
#pragma unroll
    for (int mf = 0; mf < 8; ++mf)
#pragma unroll
        for (int j = 0; j < 5; ++j) acc[mf][j] = (f32x4){0.f, 0.f, 0.f, 0.f};

    float b1v[5];
#pragma unroll
    for (int j = 0; j < 5; ++j) b1v[j] = ub1[(wid * 5 + j) * 16 + lr];

    half8 bf[5], bfn[5];
#pragma unroll
    for (int j = 0; j < 5; ++j)     // preload kc=0 (independent of Hl)
        bf[j] = *(const half8*)(W1p + ((size_t)((wid * 5 + j) * 20) * 64 + l) * 8);

    // ---- stage K-half 0: x_s(cols 0..63) + MU(64..191) + SD(192..319) ----
#pragma unroll
    for (int i = 0; i < 10; ++i) {
        int idx = tid + i * 512;              // 5120 groups
        if (idx < 1024) {
            int n_l = idx >> 3, c8 = idx & 7;
            uint4 v = {0, 0, 0, 0};
            if (n0 + n_l < N_NODES) v = xs16[(size_t)(n0 + n_l) * 8 + c8];
            *(uint4*)&Hl[n_l * 328 + c8 * 8] = v;
        } else {
            int j = idx - 1024;               // 0..4095
            int n_l = j >> 5, g = j & 31;
            int r = g >> 4, c16 = g & 15;
            uint4 v = {0, 0, 0, 0};
            if (n0 + n_l < N_NODES) v = st4[r][(size_t)(n0 + n_l) * 16 + c16];
            *(uint4*)&Hl[n_l * 328 + 64 + r * 128 + c16 * 8] = v;
        }
    }
    __syncthreads();

    // ---- layer1 half 0: kc 0..9 (bfn prefetch one kc ahead) ----
#pragma unroll
    for (int kcl = 0; kcl < 10; ++kcl) {
#pragma unroll
        for (int j = 0; j < 5; ++j)
            bfn[j] = *(const half8*)(W1p + ((size_t)((wid * 5 + j) * 20 + kcl + 1) * 64 + l) * 8);
        half8 a[8];
#pragma unroll
        for (int mf = 0; mf < 8; ++mf)
            a[mf] = *(const half8*)&Hl[(mf * 16 + lr) * 328 + kcl * 32 + lq * 8];
#pragma unroll
        for (int j = 0; j < 5; ++j)
#pragma unroll
            for (int mf = 0; mf < 8; ++mf)
                acc[mf][j] = __builtin_amdgcn_mfma_f32_16x16x32_f16(a[mf], bf[j], acc[mf][j], 0, 0, 0);
#pragma unroll
        for (int j = 0; j < 5; ++j) bf[j] = bfn[j];
    }
    __syncthreads();   // half-0 reads done

    // ---- stage K-half 1: SK(local 0..127) + KU(128..255) + x_u(256..319) ----
#pragma unroll
    for (int i = 0; i < 10; ++i) {
        int idx = tid + i * 512;
        if (idx < 4096) {
            int n_l = idx >> 5, g = idx & 31;
            int rr = g >> 4, c16 = g & 15;
            uint4 v = {0, 0, 0, 0};
            if (n0 + n_l < N_NODES) v = st4[2 + rr][(size_t)(n0 + n_l) * 16 + c16];
            *(uint4*)&Hl[n_l * 328 + rr * 128 + c16 * 8] = v;
        } else {
            int j = idx - 4096;               // 0..1023
            int n_l = j >> 3, c8 = j & 7;
            f4 aa = ((const f4*)x_u)[c8 * 2];
            f4 bb = ((const f4*)x_u)[c8 * 2 + 1];
            _Float16 hh[8] = {(_Float16)aa.x, (_Float16)aa.y, (_Float16)aa.z, (_Float16)aa.w,
                              (_Float16)bb.x, (_Float16)bb.y, (_Float16)bb.z, (_Float16)bb.w};
            *(uint4*)&Hl[n_l * 328 + 256 + c8 * 8] = *(uint4*)hh;
        }
    }
    __syncthreads();

    // ---- layer1 half 1: kc 10..19 ----
#pragma unroll
    for (int kcl = 0; kcl < 10; ++kcl) {
        if (kcl < 9) {
#pragma unroll
            for (int j = 0; j < 5; ++j)
                bfn[j] = *(const half8*)(W1p + ((size_t)((wid * 5 + j) * 20 + kcl + 11) * 64 + l) * 8);
        }
        half8 a[8];
#pragma unroll
        for (int mf = 0; mf < 8; ++mf)
            a[mf] = *(const half8*)&Hl[(mf * 16 + lr) * 328 + kcl * 32 + lq * 8];
#pragma unroll
        for (int j = 0; j < 5; ++j)
#pragma unroll
            for (int mf = 0; mf < 8; ++mf)
                acc[mf][j] = __builtin_amdgcn_mfma_f32_16x16x32_f16(a[mf], bf[j], acc[mf][j], 0, 0, 0);
#pragma unroll
        for (int j = 0; j < 5; ++j) bf[j] = bfn[j];
    }
    __syncthreads();   // all layer1 reads done; Hl free

    // ---- h1 writeback phase A (waves 0..3: cols 0..319) + layer2 kc 0..9 ----
    if (wid < 4) {
#pragma unroll
        for (int j = 0; j < 5; ++j) {
            int col = (wid * 5 + j) * 16 + lr;
#pragma unroll
            for (int mf = 0; mf < 8; ++mf)
#pragma unroll
                for (int i = 0; i < 4; ++i) {
                    int row = mf * 16 + lq * 4 + i;
                    Hl[row * 328 + col] = (_Float16)lrelu(acc[mf][j][i] + b1v[j]);
                }
        }
    }
    __syncthreads();

    f32x4 acc2[4];
#pragma unroll
    for (int ff = 0; ff < 4; ++ff) acc2[ff] = (f32x4){0.f, 0.f, 0.f, 0.f};

    for (int kc = 0; kc < 10; ++kc) {
#pragma unroll
        for (int ff = 0; ff < 4; ++ff) {
            int f = wid + ff * 8;             // 0..31: mf2 = f>>2, nf2 = f&3
            int mf2 = f >> 2, nf2 = f & 3;
            half8 a = *(const half8*)&Hl[(mf2 * 16 + lr) * 328 + kc * 32 + lq * 8];
            half8 b = *(const half8*)(W2p + ((size_t)(nf2 * 20 + kc) * 64 + l) * 8);
            acc2[ff] = __builtin_amdgcn_mfma_f32_16x16x32_f16(a, b, acc2[ff], 0, 0, 0);
        }
    }
    __syncthreads();

    // ---- h1 writeback phase B (waves 4..7: cols 320..639 -> local 0..319) + kc 10..19 --
    if (wid >= 4) {
#pragma unroll
        for (int j = 0; j < 5; ++j) {
            int col = (wid * 5 + j) * 16 + lr - 320;
#pragma unroll
            for (int mf = 0; mf < 8; ++mf)
#pragma unroll
                for (int i = 0; i < 4; ++i) {
                    int row = mf * 16 + lq * 4 + i;
                    Hl[row * 328 + col] = (_Float16)lrelu(acc[mf][j][i] + b1v[j]);
                }
        }
    }
    __syncthreads();

    for (int kc = 10; kc < 20; ++kc) {
        int kcl = kc - 10;
#pragma unroll
        for (int ff = 0; ff < 4; ++ff) {
            int f = wid + ff * 8;
            int mf2 = f >> 2, nf2 = f & 3;
            half8 a = *(const half8*)&Hl[(mf2 * 16 + lr) * 328 + kcl * 32 + lq * 8];
            half8 b = *(const half8*)(W2p + ((size_t)(nf2 * 20 + kc) * 64 + l) * 8);
            acc2[ff] = __builtin_amdgcn_mfma_f32_16x16x32_f16(a, b, acc2[ff], 0, 0, 0);
        }
    }
    __syncthreads();

    // ---- epilogue: bias2 -> Sb bounce -> hout + BN partials ----
    float* Sb = (float*)Hl;                   // [128][68] f32 = 34,816 B
#pragma unroll
    for (int ff = 0; ff < 4; ++ff) {
        int f = wid + ff * 8;
        int mf2 = f >> 2, nf2 = f & 3;
        float b2v = ub2[nf2 * 16 + lr];
#pragma unroll
        for (int i = 0; i < 4; ++i) {
            int row = mf2 * 16 + lq * 4 + i;
            Sb[row * 68 + nf2 * 16 + lr] = acc2[ff][i] + b2v;
        }
    }
    __syncthreads();

#pragma unroll
    for (int i = 0; i < 4; ++i) {             // hout: 2048 f4-groups (128 n x 16 c4)
        int idx = tid + i * 512;
        int n_l = idx >> 4, c4 = idx & 15;
        if (n0 + n_l < N_NODES) {
            f4 v = *(f4*)&Sb[n_l * 68 + c4 * 4];
            ((f4*)hout)[(size_t)(n0 + n_l) * 16 + c4] = v;
        }
    }
    if (tid < 64) {
        float ps = 0.f, pq = 0.f;
        int nmax = min(128, N_NODES - n0);
        for (int n = 0; n < nmax; ++n) {
            float v = Sb[n * 68 + tid];
            ps += v; pq += v * v;
        }
        atomicAdd(&bn_acc[tid], ps);
        atomicAdd(&bn_acc[64 + tid], pq);
    }
}

// ---------------- K5: BN finalize (in place on d_out) ----------------
__global__ __launch_bounds__(256) void k5_bnorm(
    const float* __restrict__ bn_acc,
    const float* __restrict__ gamma, const float* __restrict__ beta,
    float* __restrict__ out)
{
    int idx = blockIdx.x * 256 + threadIdx.x;
    int c = idx & 63;
    float mu = bn_acc[c] / (float)N_NODES;
    float var = bn_acc[64 + c] / (float)N_NODES - mu * mu;
    float inv = rsqrtf(var + 1e-5f);
    out[idx] = gamma[c] * (out[idx] - mu) * inv + beta[c];
}

extern "C" void kernel_launch(void* const* d_in, const int* in_sizes, int n_in,
                              void* d_out, int out_size, void* d_ws, size_t ws_size,
                              hipStream_t stream)
{
    const float* x_s = (const float*)d_in[0];
    const float* x_t = (const float*)d_in[1];
    const float* ea  = (const float*)d_in[2];
    const float* x_u = (const float*)d_in[3];
    const float* mW1 = (const float*)d_in[4];
    const float* mb1 = (const float*)d_in[5];
    const float* mW2 = (const float*)d_in[6];
    const float* mb2 = (const float*)d_in[7];
    const float* uW1 = (const float*)d_in[8];
    const float* ub1 = (const float*)d_in[9];
    const float* uW2 = (const float*)d_in[10];
    const float* ub2 = (const float*)d_in[11];
    const float* gam = (const float*)d_in[12];
    const float* bet = (const float*)d_in[13];
    const int* ei    = (const int*)d_in[14];
    const int* src = ei;
    const int* tgt = ei + N_EDGES;

    // ws layout (bytes): cur | bn | slot | msg | MU/SD/SK/KU | W1p W2p W1e W2e | xt16 xs16
    char* base = (char*)d_ws;
    int* cur   = (int*)base;
    float* bn  = (float*)(base + 401408);
    int* slot  = (int*)(base + 401920);
    unsigned short* msg = (unsigned short*)(base + 26001920);
    unsigned short* MU  = (unsigned short*)(base + 230801920);
    unsigned short* SD  = (unsigned short*)(base + 256401920);
    unsigned short* SK  = (unsigned short*)(base + 282001920);
    unsigned short* KU  = (unsigned short*)(base + 307601920);
    _Float16* W1p  = (_Float16*)(base + 333201920);
    _Float16* W2p  = (_Float16*)(base + 334021120);
    _Float16* W1e  = (_Float16*)(base + 334103040);
    _Float16* W2e  = (_Float16*)(base + 334135808);
    _Float16* xt16 = (_Float16*)(base + 334168576);   // 12.8 MB
    _Float16* xs16 = (_Float16*)(base + 346968576);   // 12.8 MB -> ends 359,768,576
    float* out = (float*)d_out;

    hipMemsetAsync(d_ws, 0, 401920, stream);

    k0_pack<<<236, 256, 0, stream>>>(uW1, uW2, mW1, mW2, W1p, W2p, W1e, W2e);
    k_xt<<<12500, 256, 0, stream>>>(x_t, xt16, x_s, xs16);
    k_slot<<<N_EDGES / 256, 256, 0, stream>>>(src, cur, slot);
    k1_mfma<<<N_EDGES / 128, 512, 0, stream>>>(xt16, ea, W1e, mb1, W2e, mb2, tgt, msg);
    k_agg<<<N_NODES / 4, 256, 0, stream>>>(cur, slot, msg, MU, SD, SK, KU);
    k3_mfma<<<(N_NODES + 127) / 128, 512, 0, stream>>>(xs16, x_u, MU, SD, SK, KU,
                                                       W1p, ub1, W2p, ub2, out, bn);
    k5_bnorm<<<(N_NODES * 64) / 256, 256, 0, stream>>>(bn, gam, bet, out);
}

// Round 21
// 518.520 us; speedup vs baseline: 1.1965x; 1.1965x over previous
//
#include <hip/hip_runtime.h>
#include <hip/hip_fp16.h>

#define N_NODES 100000
#define N_EDGES 800000
#define SLOT_CAP 64

typedef float4 f4;
typedef _Float16 half8 __attribute__((ext_vector_type(8)));
typedef float f32x4 __attribute__((ext_vector_type(4)));

__device__ __forceinline__ float lrelu(float x) { return x > 0.f ? x : 0.01f * x; }

__device__ __forceinline__ float2 h2f2(unsigned u) {
    union { unsigned w; __half2 h; } cv; cv.w = u;
    return __half22float2(cv.h);
}
__device__ __forceinline__ unsigned f2h2(float lo, float hi) {
    union { unsigned w; __half2 h; } cv; cv.h = __floats2half2_rn(lo, hi);
    return cv.w;
}

// ---------------- K0: pack all four weight matrices into MFMA b-frag layout (f16) -------
__global__ __launch_bounds__(256) void k0_pack(
    const float* __restrict__ uW1, const float* __restrict__ uW2,
    const float* __restrict__ mW1, const float* __restrict__ mW2,
    _Float16* __restrict__ W1p, _Float16* __restrict__ W2p,
    _Float16* __restrict__ W1e, _Float16* __restrict__ W2e)
{
    int t = blockIdx.x * 256 + threadIdx.x;   // 236*256 = 60416 slots total
    const float* W; _Float16* P; int s, KC, ldk;
    if (t < 51200)      { W = uW1; P = W1p; s = t;         KC = 20; ldk = 640; }
    else if (t < 56320) { W = uW2; P = W2p; s = t - 51200; KC = 20; ldk = 640; }
    else if (t < 58368) { W = mW1; P = W1e; s = t - 56320; KC = 4;  ldk = 128; }
    else                { W = mW2; P = W2e; s = t - 58368; KC = 4;  ldk = 128; }
    int nf = s / (KC * 64), r1 = s % (KC * 64), kc = r1 >> 6, l = r1 & 63;
    int row = nf * 16 + (l & 15);
    int k0 = kc * 32 + (l >> 4) * 8;
    const float* sp = W + (size_t)row * ldk + k0;
    _Float16 h[8];
#pragma unroll
    for (int i = 0; i < 8; ++i) h[i] = (_Float16)sp[i];
    *(uint4*)(P + (size_t)s * 8) = *(uint4*)h;
}

// ---------------- K_xt: convert x_t AND x_s (f32) -> fp16 (L2-friendly) ----------------
__global__ __launch_bounds__(256) void k_xt(
    const float* __restrict__ x_t, _Float16* __restrict__ x_t16,
    const float* __restrict__ x_s, _Float16* __restrict__ x_s16)
{
    int i = blockIdx.x * 256 + threadIdx.x;    // 3.2M threads: 1.6M x_t + 1.6M x_s
    const float* src; _Float16* dst; int g;
    if (i < 1600000) { src = x_t; dst = x_t16; g = i; }
    else             { src = x_s; dst = x_s16; g = i - 1600000; }
    f4 v = ((const f4*)src)[g];
    _Float16 h[4] = {(_Float16)v.x, (_Float16)v.y, (_Float16)v.z, (_Float16)v.w};
    *(uint2*)(dst + (size_t)g * 4) = *(uint2*)h;
}

// ---------------- K_slot: per-node edge-list build (atomics isolated) ------------------
__global__ __launch_bounds__(256) void k_slot(
    const int* __restrict__ src, int* __restrict__ cur, int* __restrict__ slot)
{
    int e = blockIdx.x * 256 + threadIdx.x;   // exactly N_EDGES
    int s = src[e];
    int pos = atomicAdd(&cur[s], 1);
    if (pos < SLOT_CAP) slot[s * SLOT_CAP + pos] = e;
}

// ---------------- K1: edge MLP (128->128->128) via f16 MFMA, W staged in LDS ----------
__global__ __launch_bounds__(512) void k1_mfma(
    const _Float16* __restrict__ x_t16, const float* __restrict__ ea,
    const _Float16* __restrict__ W1e, const float* __restrict__ mb1,
    const _Float16* __restrict__ W2e, const float* __restrict__ mb2,
    const int* __restrict__ tgt, unsigned short* __restrict__ msg)
{
    __shared__ _Float16 T[128 * 136];      // 34,816 B
    __shared__ _Float16 Wl[16384];         // 32,768 B
    const int tid = threadIdx.x;
    const int wid = tid >> 6, l = tid & 63;
    const int lr = l & 15, lq = l >> 4;
    const int e0 = blockIdx.x * 128;

    {
        const uint4* xt16 = (const uint4*)x_t16;
        const f4* ea4 = (const f4*)ea;
#pragma unroll
        for (int i = 0; i < 6; ++i) {
            int idx = tid + i * 512;           // 3072 groups: 1024 x_t16 + 2048 ea
            if (idx < 1024) {
                int e = idx >> 3, c8 = idx & 7;
                int tg = tgt[e0 + e];
                uint4 v = xt16[(size_t)tg * 8 + c8];
                *(uint4*)&T[e * 136 + c8 * 8] = v;
            } else {
                int j = idx - 1024;
                int e = j >> 4, c4 = j & 15;
                f4 v = ea4[(size_t)(e0 + e) * 16 + c4];
                _Float16 h[4] = {(_Float16)v.x, (_Float16)v.y, (_Float16)v.z, (_Float16)v.w};
                *(uint2*)&T[e * 136 + 64 + c4 * 4] = *(uint2*)h;
            }
        }
#pragma unroll
        for (int i = 0; i < 4; ++i) {
            int idx = tid + i * 512;           // 2048 uint4 = 32 KB
            ((uint4*)Wl)[idx] = ((const uint4*)W1e)[idx];
        }
    }
    __syncthreads();

    f32x4 acc[8];
#pragma unroll
    for (int nf = 0; nf < 8; ++nf) acc[nf] = (f32x4){0.f, 0.f, 0.f, 0.f};

    for (int kc = 0; kc < 4; ++kc) {
        half8 a = *(const half8*)&T[(wid * 16 + lr) * 136 + kc * 32 + lq * 8];
#pragma unroll
        for (int nf = 0; nf < 8; ++nf) {
            half8 b = *(const half8*)&Wl[((nf * 4 + kc) * 64 + l) * 8];
            acc[nf] = __builtin_amdgcn_mfma_f32_16x16x32_f16(a, b, acc[nf], 0, 0, 0);
        }
    }

#pragma unroll
    for (int nf = 0; nf < 8; ++nf) {
        float b1 = mb1[nf * 16 + lr];
#pragma unroll
        for (int i = 0; i < 4; ++i) {
            int row = wid * 16 + lq * 4 + i;
            T[row * 136 + nf * 16 + lr] = (_Float16)lrelu(acc[nf][i] + b1);
        }
    }
    __syncthreads();

#pragma unroll
    for (int i = 0; i < 4; ++i) {
        int idx = tid + i * 512;
        ((uint4*)Wl)[idx] = ((const uint4*)W2e)[idx];
    }
    __syncthreads();

#pragma unroll
    for (int nf = 0; nf < 8; ++nf) acc[nf] = (f32x4){0.f, 0.f, 0.f, 0.f};

    for (int kc = 0; kc < 4; ++kc) {
        half8 a = *(const half8*)&T[(wid * 16 + lr) * 136 + kc * 32 + lq * 8];
#pragma unroll
        for (int nf = 0; nf < 8; ++nf) {
            half8 b = *(const half8*)&Wl[((nf * 4 + kc) * 64 + l) * 8];
            acc[nf] = __builtin_amdgcn_mfma_f32_16x16x32_f16(a, b, acc[nf], 0, 0, 0);
        }
    }

#pragma unroll
    for (int nf = 0; nf < 8; ++nf) {
        float b2 = mb2[nf * 16 + lr];
#pragma unroll
        for (int i = 0; i < 4; ++i) {
            int row = wid * 16 + lq * 4 + i;
            T[row * 136 + nf * 16 + lr] = (_Float16)(acc[nf][i] + b2);
        }
    }
    __syncthreads();

#pragma unroll
    for (int i = 0; i < 4; ++i) {
        int idx = tid + i * 512;
        int row = idx >> 4, g = idx & 15;
        uint4 v = *(const uint4*)&T[row * 136 + g * 8];
        ((uint4*)(msg + (size_t)(e0 + row) * 128))[g] = v;
    }
}

// ---------------- K2: gather aggregation, one wave per node ----------------
__global__ __launch_bounds__(256) void k_agg(
    const int* __restrict__ cur, const int* __restrict__ slot,
    const unsigned short* __restrict__ msg,
    unsigned short* __restrict__ MU, unsigned short* __restrict__ SD,
    unsigned short* __restrict__ SK, unsigned short* __restrict__ KU)
{
    const int n = (blockIdx.x * 256 + threadIdx.x) >> 6;
    const int lane = threadIdx.x & 63;
    const int deg = cur[n];
    const int m = min(deg, SLOT_CAP);
    const unsigned* msg2 = (const unsigned*)msg;
    const int sl = slot[(size_t)n * SLOT_CAP + lane];

    unsigned uc[16];
    float s1a = 0.f, s1b = 0.f, s2a = 0.f, s2b = 0.f;
#pragma unroll
    for (int i = 0; i < 16; ++i) {
        if (i < m) {
            int e = __shfl(sl, i);
            unsigned u = msg2[(size_t)e * 64 + lane];
            uc[i] = u;
            float2 f = h2f2(u);
            s1a += f.x; s2a += f.x * f.x; s1b += f.y; s2b += f.y * f.y;
        }
    }
    for (int i = 16; i < m; ++i) {
        int e = __shfl(sl, i);
        float2 f = h2f2(msg2[(size_t)e * 64 + lane]);
        s1a += f.x; s2a += f.x * f.x; s1b += f.y; s2b += f.y * f.y;
    }

    float inv = 1.f / fmaxf((float)deg, 1.f);
    float mua = s1a * inv, mub = s1b * inv;
    float vra = s2a * inv - mua * mua; vra = vra > 0.f ? vra : 0.01f * vra;
    float vrb = s2b * inv - mub * mub; vrb = vrb > 0.f ? vrb : 0.01f * vrb;
    float sda = sqrtf(vra + 1e-6f), sdb = sqrtf(vrb + 1e-6f);

    float c3a = 0.f, c4a = 0.f, c3b = 0.f, c4b = 0.f;
#pragma unroll
    for (int i = 0; i < 16; ++i) {
        if (i < m) {
            float2 f = h2f2(uc[i]);
            float ca = f.x - mua, cb = f.y - mub;
            float c2a = ca * ca, c2b = cb * cb;
            c3a += c2a * ca; c4a += c2a * c2a; c3b += c2b * cb; c4b += c2b * c2b;
        }
    }
    for (int i = 16; i < m; ++i) {
        int e = __shfl(sl, i);
        float2 f = h2f2(msg2[(size_t)e * 64 + lane]);
        float ca = f.x - mua, cb = f.y - mub;
        float c2a = ca * ca, c2b = cb * cb;
        c3a += c2a * ca; c4a += c2a * c2a; c3b += c2b * cb; c4b += c2b * c2b;
    }

    float ska = c3a * inv / (sda * sda * sda);
    float skb = c3b * inv / (sdb * sdb * sdb);
    float p;
    p = sda * sda; float kua = c4a * inv / (p * p);
    p = sdb * sdb; float kub = c4b * inv / (p * p);

    size_t o = (size_t)n * 64 + lane;
    ((unsigned*)MU)[o] = f2h2(mua, mub);
    ((unsigned*)SD)[o] = f2h2(sda, sdb);
    ((unsigned*)SK)[o] = f2h2(ska, skb);
    ((unsigned*)KU)[o] = f2h2(kua, kub);
}

// ---------------- K3 v3b: node MLP, 80 nodes/block (r17/r19 winner) --------------------
// Best measured (r19: 195us). r20's 8:1 variant spilled (WRITE_SIZE 25->239MB) and
// regressed to 297us; r18's 48n/2-blocks and r15's coop-stage also regressed.
// 5:1 MFMA:b-load at 80n/block, VGPR=88, is the empirical optimum of this space.
__global__ __launch_bounds__(512, 2) void k3_mfma(
    const _Float16* __restrict__ x_s16, const float* __restrict__ x_u,
    const unsigned short* __restrict__ MU, const unsigned short* __restrict__ SD,
    const unsigned short* __restrict__ SK, const unsigned short* __restrict__ KU,
    const _Float16* __restrict__ W1p, const float* __restrict__ ub1,
    const _Float16* __restrict__ W2p, const float* __restrict__ ub2,
    float* __restrict__ hout, float* __restrict__ bn_acc)
{
    __shared__ _Float16 Hl[80 * 648];     // 103,680 B
    const int tid = threadIdx.x;
    const int wid = tid >> 6, l = tid & 63;
    const int lr = l & 15, lq = l >> 4;
    const int n0 = blockIdx.x * 80;

    // ---- stage H tile (f16): [80][648] ----
    {
        const uint4* xs16 = (const uint4*)x_s16;
#pragma unroll
        for (int i = 0; i < 2; ++i) {         // x_s16: 640 uint4-groups (80 n x 8 c8)
            int idx = tid + i * 512;
            if (idx < 640) {
                int n_l = idx >> 3, c8 = idx & 7;
                uint4 v = xs16[(size_t)(n0 + n_l) * 8 + c8];
                *(uint4*)&Hl[n_l * 648 + c8 * 8] = v;
            }
        }
        const uint4* st4[4] = {(const uint4*)MU, (const uint4*)SD,
                               (const uint4*)SK, (const uint4*)KU};
#pragma unroll
        for (int i = 0; i < 10; ++i) {        // stats: 5120 uint4-groups (80n x 4r x 16)
            int idx = tid + i * 512;
            int n_l = idx >> 6, g = idx & 63;
            int r = g >> 4, c16 = g & 15;
            uint4 u = st4[r][(size_t)(n0 + n_l) * 16 + c16];
            *(uint4*)&Hl[n_l * 648 + 64 + r * 128 + c16 * 8] = u;
        }
#pragma unroll
        for (int i = 0; i < 2; ++i) {         // x_u: 640 uint4-groups (broadcast)
            int idx = tid + i * 512;
            if (idx < 640) {
                int n_l = idx >> 3, c8 = idx & 7;
                f4 a = ((const f4*)x_u)[c8 * 2];
                f4 b = ((const f4*)x_u)[c8 * 2 + 1];
                _Float16 h[8] = {(_Float16)a.x, (_Float16)a.y, (_Float16)a.z, (_Float16)a.w,
                                 (_Float16)b.x, (_Float16)b.y, (_Float16)b.z, (_Float16)b.w};
                *(uint4*)&Hl[n_l * 648 + 576 + c8 * 8] = *(uint4*)h;
            }
        }
    }
    __syncthreads();

    // ---- layer 1: wave wid -> nf in [wid*5, wid*5+5), 5 mf x 5 nf ----
    f32x4 acc[5][5];
#pragma unroll
    for (int mf = 0; mf < 5; ++mf)
#pragma unroll
        for (int j = 0; j < 5; ++j) acc[mf][j] = (f32x4){0.f, 0.f, 0.f, 0.f};

    float b1v[5];
#pragma unroll
    for (int j = 0; j < 5; ++j) b1v[j] = ub1[(wid * 5 + j) * 16 + lr];

    for (int kc = 0; kc < 20; ++kc) {
        half8 a[5];
#pragma unroll
        for (int mf = 0; mf < 5; ++mf)
            a[mf] = *(const half8*)&Hl[(mf * 16 + lr) * 648 + kc * 32 + lq * 8];
#pragma unroll
        for (int j = 0; j < 5; ++j) {
            half8 b = *(const half8*)(W1p + ((size_t)((wid * 5 + j) * 20 + kc) * 64 + l) * 8);
#pragma unroll
            for (int mf = 0; mf < 5; ++mf)
                acc[mf][j] = __builtin_amdgcn_mfma_f32_16x16x32_f16(a[mf], b, acc[mf][j], 0, 0, 0);
        }
    }

    __syncthreads();   // all layer-1 reads of Hl done
#pragma unroll
    for (int mf = 0; mf < 5; ++mf)
#pragma unroll
        for (int j = 0; j < 5; ++j) {
            int col = (wid * 5 + j) * 16 + lr;
#pragma unroll
            for (int i = 0; i < 4; ++i) {
                int row = mf * 16 + lq * 4 + i;
                Hl[row * 648 + col] = (_Float16)lrelu(acc[mf][j][i] + b1v[j]);
            }
        }
    __syncthreads();

    // ---- layer 2: 20 frags (5 mf x 4 nf) over 8 waves: f = wid, wid+8, wid+16 ----
    f32x4 acc2[3];
    acc2[0] = (f32x4){0.f, 0.f, 0.f, 0.f};
    acc2[1] = (f32x4){0.f, 0.f, 0.f, 0.f};
    acc2[2] = (f32x4){0.f, 0.f, 0.f, 0.f};

    for (int kc = 0; kc < 20; ++kc) {
#pragma unroll
        for (int ff = 0; ff < 3; ++ff) {
            int f = wid + ff * 8;
            if (f < 20) {
                int mf2 = f >> 2, nf2 = f & 3;
                half8 a = *(const half8*)&Hl[(mf2 * 16 + lr) * 648 + kc * 32 + lq * 8];
                half8 b = *(const half8*)(W2p + ((size_t)(nf2 * 20 + kc) * 64 + l) * 8);
                acc2[ff] = __builtin_amdgcn_mfma_f32_16x16x32_f16(a, b, acc2[ff], 0, 0, 0);
            }
        }
    }

    __syncthreads();   // all layer-2 reads of Hl done
    float* Sb = (float*)Hl;      // reuse as [80][68] f32 bounce
#pragma unroll
    for (int ff = 0; ff < 3; ++ff) {
        int f = wid + ff * 8;
        if (f < 20) {
            int mf2 = f >> 2, nf2 = f & 3;
            float b2v = ub2[nf2 * 16 + lr];
#pragma unroll
            for (int i = 0; i < 4; ++i) {
                int row = mf2 * 16 + lq * 4 + i;
                Sb[row * 68 + nf2 * 16 + lr] = acc2[ff][i] + b2v;
            }
        }
    }
    __syncthreads();

#pragma unroll
    for (int i = 0; i < 3; ++i) {            // hout: 1280 f4-groups
        int idx = tid + i * 512;
        if (idx < 1280) {
            int n_l = idx >> 4, c4 = idx & 15;
            f4 v = *(f4*)&Sb[n_l * 68 + c4 * 4];
            ((f4*)hout)[(size_t)(n0 + n_l) * 16 + c4] = v;
        }
    }
    if (tid < 64) {
        float ps = 0.f, pq = 0.f;
#pragma unroll 4
        for (int n = 0; n < 80; ++n) {
            float v = Sb[n * 68 + tid];
            ps += v; pq += v * v;
        }
        atomicAdd(&bn_acc[tid], ps);
        atomicAdd(&bn_acc[64 + tid], pq);
    }
}

// ---------------- K5: BN finalize (in place on d_out) ----------------
__global__ __launch_bounds__(256) void k5_bnorm(
    const float* __restrict__ bn_acc,
    const float* __restrict__ gamma, const float* __restrict__ beta,
    float* __restrict__ out)
{
    int idx = blockIdx.x * 256 + threadIdx.x;
    int c = idx & 63;
    float mu = bn_acc[c] / (float)N_NODES;
    float var = bn_acc[64 + c] / (float)N_NODES - mu * mu;
    float inv = rsqrtf(var + 1e-5f);
    out[idx] = gamma[c] * (out[idx] - mu) * inv + beta[c];
}

extern "C" void kernel_launch(void* const* d_in, const int* in_sizes, int n_in,
                              void* d_out, int out_size, void* d_ws, size_t ws_size,
                              hipStream_t stream)
{
    const float* x_s = (const float*)d_in[0];
    const float* x_t = (const float*)d_in[1];
    const float* ea  = (const float*)d_in[2];
    const float* x_u = (const float*)d_in[3];
    const float* mW1 = (const float*)d_in[4];
    const float* mb1 = (const float*)d_in[5];
    const float* mW2 = (const float*)d_in[6];
    const float* mb2 = (const float*)d_in[7];
    const float* uW1 = (const float*)d_in[8];
    const float* ub1 = (const float*)d_in[9];
    const float* uW2 = (const float*)d_in[10];
    const float* ub2 = (const float*)d_in[11];
    const float* gam = (const float*)d_in[12];
    const float* bet = (const float*)d_in[13];
    const int* ei    = (const int*)d_in[14];
    const int* src = ei;
    const int* tgt = ei + N_EDGES;

    // ws layout (bytes): cur | bn | slot | msg | MU/SD/SK/KU | W1p W2p W1e W2e | xt16 xs16
    char* base = (char*)d_ws;
    int* cur   = (int*)base;
    float* bn  = (float*)(base + 401408);
    int* slot  = (int*)(base + 401920);
    unsigned short* msg = (unsigned short*)(base + 26001920);
    unsigned short* MU  = (unsigned short*)(base + 230801920);
    unsigned short* SD  = (unsigned short*)(base + 256401920);
    unsigned short* SK  = (unsigned short*)(base + 282001920);
    unsigned short* KU  = (unsigned short*)(base + 307601920);
    _Float16* W1p  = (_Float16*)(base + 333201920);
    _Float16* W2p  = (_Float16*)(base + 334021120);
    _Float16* W1e  = (_Float16*)(base + 334103040);
    _Float16* W2e  = (_Float16*)(base + 334135808);
    _Float16* xt16 = (_Float16*)(base + 334168576);   // 12.8 MB
    _Float16* xs16 = (_Float16*)(base + 346968576);   // 12.8 MB -> ends 359,768,576
    float* out = (float*)d_out;

    hipMemsetAsync(d_ws, 0, 401920, stream);

    k0_pack<<<236, 256, 0, stream>>>(uW1, uW2, mW1, mW2, W1p, W2p, W1e, W2e);
    k_xt<<<12500, 256, 0, stream>>>(x_t, xt16, x_s, xs16);
    k_slot<<<N_EDGES / 256, 256, 0, stream>>>(src, cur, slot);
    k1_mfma<<<N_EDGES / 128, 512, 0, stream>>>(xt16, ea, W1e, mb1, W2e, mb2, tgt, msg);
    k_agg<<<N_NODES / 4, 256, 0, stream>>>(cur, slot, msg, MU, SD, SK, KU);
    k3_mfma<<<N_NODES / 80, 512, 0, stream>>>(xs16, x_u, MU, SD, SK, KU,
                                              W1p, ub1, W2p, ub2, out, bn);
    k5_bnorm<<<(N_NODES * 64) / 256, 256, 0, stream>>>(bn, gam, bet, out);
}

// Round 22
// 482.460 us; speedup vs baseline: 1.2859x; 1.0747x over previous
//
#include <hip/hip_runtime.h>
#include <hip/hip_fp16.h>

#define N_NODES 100000
#define N_EDGES 800000
#define SLOT_CAP 64

typedef float4 f4;
typedef _Float16 half8 __attribute__((ext_vector_type(8)));
typedef float f32x4 __attribute__((ext_vector_type(4)));

__device__ __forceinline__ float lrelu(float x) { return x > 0.f ? x : 0.01f * x; }

__device__ __forceinline__ float2 h2f2(unsigned u) {
    union { unsigned w; __half2 h; } cv; cv.w = u;
    return __half22float2(cv.h);
}
__device__ __forceinline__ unsigned f2h2(float lo, float hi) {
    union { unsigned w; __half2 h; } cv; cv.h = __floats2half2_rn(lo, hi);
    return cv.w;
}

// ---------------- K0: pack all four weight matrices into MFMA b-frag layout (f16) -------
__global__ __launch_bounds__(256) void k0_pack(
    const float* __restrict__ uW1, const float* __restrict__ uW2,
    const float* __restrict__ mW1, const float* __restrict__ mW2,
    _Float16* __restrict__ W1p, _Float16* __restrict__ W2p,
    _Float16* __restrict__ W1e, _Float16* __restrict__ W2e)
{
    int t = blockIdx.x * 256 + threadIdx.x;   // 236*256 = 60416 slots total
    const float* W; _Float16* P; int s, KC, ldk;
    if (t < 51200)      { W = uW1; P = W1p; s = t;         KC = 20; ldk = 640; }
    else if (t < 56320) { W = uW2; P = W2p; s = t - 51200; KC = 20; ldk = 640; }
    else if (t < 58368) { W = mW1; P = W1e; s = t - 56320; KC = 4;  ldk = 128; }
    else                { W = mW2; P = W2e; s = t - 58368; KC = 4;  ldk = 128; }
    int nf = s / (KC * 64), r1 = s % (KC * 64), kc = r1 >> 6, l = r1 & 63;
    int row = nf * 16 + (l & 15);
    int k0 = kc * 32 + (l >> 4) * 8;
    const float* sp = W + (size_t)row * ldk + k0;
    _Float16 h[8];
#pragma unroll
    for (int i = 0; i < 8; ++i) h[i] = (_Float16)sp[i];
    *(uint4*)(P + (size_t)s * 8) = *(uint4*)h;
}

// ---------------- K_xt: convert x_t AND x_s (f32) -> fp16 (L2-friendly) ----------------
__global__ __launch_bounds__(256) void k_xt(
    const float* __restrict__ x_t, _Float16* __restrict__ x_t16,
    const float* __restrict__ x_s, _Float16* __restrict__ x_s16)
{
    int i = blockIdx.x * 256 + threadIdx.x;    // 3.2M threads: 1.6M x_t + 1.6M x_s
    const float* src; _Float16* dst; int g;
    if (i < 1600000) { src = x_t; dst = x_t16; g = i; }
    else             { src = x_s; dst = x_s16; g = i - 1600000; }
    f4 v = ((const f4*)src)[g];
    _Float16 h[4] = {(_Float16)v.x, (_Float16)v.y, (_Float16)v.z, (_Float16)v.w};
    *(uint2*)(dst + (size_t)g * 4) = *(uint2*)h;
}

// ---------------- K_slot: per-node edge-list build (atomics isolated) ------------------
__global__ __launch_bounds__(256) void k_slot(
    const int* __restrict__ src, int* __restrict__ cur, int* __restrict__ slot)
{
    int e = blockIdx.x * 256 + threadIdx.x;   // exactly N_EDGES
    int s = src[e];
    int pos = atomicAdd(&cur[s], 1);
    if (pos < SLOT_CAP) slot[s * SLOT_CAP + pos] = e;
}

// ---------------- K1: edge MLP (128->128->128) via f16 MFMA, W staged in LDS ----------
__global__ __launch_bounds__(512) void k1_mfma(
    const _Float16* __restrict__ x_t16, const float* __restrict__ ea,
    const _Float16* __restrict__ W1e, const float* __restrict__ mb1,
    const _Float16* __restrict__ W2e, const float* __restrict__ mb2,
    const int* __restrict__ tgt, unsigned short* __restrict__ msg)
{
    __shared__ _Float16 T[128 * 136];      // 34,816 B
    __shared__ _Float16 Wl[16384];         // 32,768 B
    const int tid = threadIdx.x;
    const int wid = tid >> 6, l = tid & 63;
    const int lr = l & 15, lq = l >> 4;
    const int e0 = blockIdx.x * 128;

    {
        const uint4* xt16 = (const uint4*)x_t16;
        const f4* ea4 = (const f4*)ea;
#pragma unroll
        for (int i = 0; i < 6; ++i) {
            int idx = tid + i * 512;           // 3072 groups: 1024 x_t16 + 2048 ea
            if (idx < 1024) {
                int e = idx >> 3, c8 = idx & 7;
                int tg = tgt[e0 + e];
                uint4 v = xt16[(size_t)tg * 8 + c8];
                *(uint4*)&T[e * 136 + c8 * 8] = v;
            } else {
                int j = idx - 1024;
                int e = j >> 4, c4 = j & 15;
                f4 v = ea4[(size_t)(e0 + e) * 16 + c4];
                _Float16 h[4] = {(_Float16)v.x, (_Float16)v.y, (_Float16)v.z, (_Float16)v.w};
                *(uint2*)&T[e * 136 + 64 + c4 * 4] = *(uint2*)h;
            }
        }
#pragma unroll
        for (int i = 0; i < 4; ++i) {
            int idx = tid + i * 512;           // 2048 uint4 = 32 KB
            ((uint4*)Wl)[idx] = ((const uint4*)W1e)[idx];
        }
    }
    __syncthreads();

    f32x4 acc[8];
#pragma unroll
    for (int nf = 0; nf < 8; ++nf) acc[nf] = (f32x4){0.f, 0.f, 0.f, 0.f};

    for (int kc = 0; kc < 4; ++kc) {
        half8 a = *(const half8*)&T[(wid * 16 + lr) * 136 + kc * 32 + lq * 8];
#pragma unroll
        for (int nf = 0; nf < 8; ++nf) {
            half8 b = *(const half8*)&Wl[((nf * 4 + kc) * 64 + l) * 8];
            acc[nf] = __builtin_amdgcn_mfma_f32_16x16x32_f16(a, b, acc[nf], 0, 0, 0);
        }
    }

#pragma unroll
    for (int nf = 0; nf < 8; ++nf) {
        float b1 = mb1[nf * 16 + lr];
#pragma unroll
        for (int i = 0; i < 4; ++i) {
            int row = wid * 16 + lq * 4 + i;
            T[row * 136 + nf * 16 + lr] = (_Float16)lrelu(acc[nf][i] + b1);
        }
    }
    __syncthreads();

#pragma unroll
    for (int i = 0; i < 4; ++i) {
        int idx = tid + i * 512;
        ((uint4*)Wl)[idx] = ((const uint4*)W2e)[idx];
    }
    __syncthreads();

#pragma unroll
    for (int nf = 0; nf < 8; ++nf) acc[nf] = (f32x4){0.f, 0.f, 0.f, 0.f};

    for (int kc = 0; kc < 4; ++kc) {
        half8 a = *(const half8*)&T[(wid * 16 + lr) * 136 + kc * 32 + lq * 8];
#pragma unroll
        for (int nf = 0; nf < 8; ++nf) {
            half8 b = *(const half8*)&Wl[((nf * 4 + kc) * 64 + l) * 8];
            acc[nf] = __builtin_amdgcn_mfma_f32_16x16x32_f16(a, b, acc[nf], 0, 0, 0);
        }
    }

#pragma unroll
    for (int nf = 0; nf < 8; ++nf) {
        float b2 = mb2[nf * 16 + lr];
#pragma unroll
        for (int i = 0; i < 4; ++i) {
            int row = wid * 16 + lq * 4 + i;
            T[row * 136 + nf * 16 + lr] = (_Float16)(acc[nf][i] + b2);
        }
    }
    __syncthreads();

#pragma unroll
    for (int i = 0; i < 4; ++i) {
        int idx = tid + i * 512;
        int row = idx >> 4, g = idx & 15;
        uint4 v = *(const uint4*)&T[row * 136 + g * 8];
        ((uint4*)(msg + (size_t)(e0 + row) * 128))[g] = v;
    }
}

// ---------------- K2: gather aggregation, one wave per node ----------------
__global__ __launch_bounds__(256) void k_agg(
    const int* __restrict__ cur, const int* __restrict__ slot,
    const unsigned short* __restrict__ msg,
    unsigned short* __restrict__ MU, unsigned short* __restrict__ SD,
    unsigned short* __restrict__ SK, unsigned short* __restrict__ KU)
{
    const int n = (blockIdx.x * 256 + threadIdx.x) >> 6;
    const int lane = threadIdx.x & 63;
    const int deg = cur[n];
    const int m = min(deg, SLOT_CAP);
    const unsigned* msg2 = (const unsigned*)msg;
    const int sl = slot[(size_t)n * SLOT_CAP + lane];

    unsigned uc[16];
    float s1a = 0.f, s1b = 0.f, s2a = 0.f, s2b = 0.f;
#pragma unroll
    for (int i = 0; i < 16; ++i) {
        if (i < m) {
            int e = __shfl(sl, i);
            unsigned u = msg2[(size_t)e * 64 + lane];
            uc[i] = u;
            float2 f = h2f2(u);
            s1a += f.x; s2a += f.x * f.x; s1b += f.y; s2b += f.y * f.y;
        }
    }
    for (int i = 16; i < m; ++i) {
        int e = __shfl(sl, i);
        float2 f = h2f2(msg2[(size_t)e * 64 + lane]);
        s1a += f.x; s2a += f.x * f.x; s1b += f.y; s2b += f.y * f.y;
    }

    float inv = 1.f / fmaxf((float)deg, 1.f);
    float mua = s1a * inv, mub = s1b * inv;
    float vra = s2a * inv - mua * mua; vra = vra > 0.f ? vra : 0.01f * vra;
    float vrb = s2b * inv - mub * mub; vrb = vrb > 0.f ? vrb : 0.01f * vrb;
    float sda = sqrtf(vra + 1e-6f), sdb = sqrtf(vrb + 1e-6f);

    float c3a = 0.f, c4a = 0.f, c3b = 0.f, c4b = 0.f;
#pragma unroll
    for (int i = 0; i < 16; ++i) {
        if (i < m) {
            float2 f = h2f2(uc[i]);
            float ca = f.x - mua, cb = f.y - mub;
            float c2a = ca * ca, c2b = cb * cb;
            c3a += c2a * ca; c4a += c2a * c2a; c3b += c2b * cb; c4b += c2b * c2b;
        }
    }
    for (int i = 16; i < m; ++i) {
        int e = __shfl(sl, i);
        float2 f = h2f2(msg2[(size_t)e * 64 + lane]);
        float ca = f.x - mua, cb = f.y - mub;
        float c2a = ca * ca, c2b = cb * cb;
        c3a += c2a * ca; c4a += c2a * c2a; c3b += c2b * cb; c4b += c2b * c2b;
    }

    float ska = c3a * inv / (sda * sda * sda);
    float skb = c3b * inv / (sdb * sdb * sdb);
    float p;
    p = sda * sda; float kua = c4a * inv / (p * p);
    p = sdb * sdb; float kub = c4b * inv / (p * p);

    size_t o = (size_t)n * 64 + lane;
    ((unsigned*)MU)[o] = f2h2(mua, mub);
    ((unsigned*)SD)[o] = f2h2(sda, sdb);
    ((unsigned*)SK)[o] = f2h2(ska, skb);
    ((unsigned*)KU)[o] = f2h2(kua, kub);
}

// ---------------- K3 v7: r19 shape (80n, 5:1) + register-double-buffered b-frags -------
// r20's spill was a budget error at 8mf (acc=160 + prefetch 40 > 256). At 5mf:
// acc 100 + bf 20 + bfn 20 + a 20 + misc ~25 = ~185 < 256 cap -> fits. Per-kc chain
// (5 loads -> wait -> 25 MFMA) becomes (issue bfn -> 25 MFMA on bf -> swap).
__global__ __launch_bounds__(512, 2) void k3_mfma(
    const _Float16* __restrict__ x_s16, const float* __restrict__ x_u,
    const unsigned short* __restrict__ MU, const unsigned short* __restrict__ SD,
    const unsigned short* __restrict__ SK, const unsigned short* __restrict__ KU,
    const _Float16* __restrict__ W1p, const float* __restrict__ ub1,
    const _Float16* __restrict__ W2p, const float* __restrict__ ub2,
    float* __restrict__ hout, float* __restrict__ bn_acc)
{
    __shared__ _Float16 Hl[80 * 648];     // 103,680 B
    const int tid = threadIdx.x;
    const int wid = tid >> 6, l = tid & 63;
    const int lr = l & 15, lq = l >> 4;
    const int n0 = blockIdx.x * 80;

    half8 bf[5], bfn[5];
#pragma unroll
    for (int j = 0; j < 5; ++j)   // preload kc=0 b-frags (independent of LDS staging)
        bf[j] = *(const half8*)(W1p + ((size_t)((wid * 5 + j) * 20) * 64 + l) * 8);

    // ---- stage H tile (f16): [80][648] ----
    {
        const uint4* xs16 = (const uint4*)x_s16;
#pragma unroll
        for (int i = 0; i < 2; ++i) {         // x_s16: 640 uint4-groups (80 n x 8 c8)
            int idx = tid + i * 512;
            if (idx < 640) {
                int n_l = idx >> 3, c8 = idx & 7;
                uint4 v = xs16[(size_t)(n0 + n_l) * 8 + c8];
                *(uint4*)&Hl[n_l * 648 + c8 * 8] = v;
            }
        }
        const uint4* st4[4] = {(const uint4*)MU, (const uint4*)SD,
                               (const uint4*)SK, (const uint4*)KU};
#pragma unroll
        for (int i = 0; i < 10; ++i) {        // stats: 5120 uint4-groups (80n x 4r x 16)
            int idx = tid + i * 512;
            int n_l = idx >> 6, g = idx & 63;
            int r = g >> 4, c16 = g & 15;
            uint4 u = st4[r][(size_t)(n0 + n_l) * 16 + c16];
            *(uint4*)&Hl[n_l * 648 + 64 + r * 128 + c16 * 8] = u;
        }
#pragma unroll
        for (int i = 0; i < 2; ++i) {         // x_u: 640 uint4-groups (broadcast)
            int idx = tid + i * 512;
            if (idx < 640) {
                int n_l = idx >> 3, c8 = idx & 7;
                f4 a = ((const f4*)x_u)[c8 * 2];
                f4 b = ((const f4*)x_u)[c8 * 2 + 1];
                _Float16 h[8] = {(_Float16)a.x, (_Float16)a.y, (_Float16)a.z, (_Float16)a.w,
                                 (_Float16)b.x, (_Float16)b.y, (_Float16)b.z, (_Float16)b.w};
                *(uint4*)&Hl[n_l * 648 + 576 + c8 * 8] = *(uint4*)h;
            }
        }
    }
    __syncthreads();

    // ---- layer 1: wave wid -> nf in [wid*5, wid*5+5), 5 mf x 5 nf, b double-buffered --
    f32x4 acc[5][5];
#pragma unroll
    for (int mf = 0; mf < 5; ++mf)
#pragma unroll
        for (int j = 0; j < 5; ++j) acc[mf][j] = (f32x4){0.f, 0.f, 0.f, 0.f};

    float b1v[5];
#pragma unroll
    for (int j = 0; j < 5; ++j) b1v[j] = ub1[(wid * 5 + j) * 16 + lr];

    for (int kc = 0; kc < 20; ++kc) {
        if (kc < 19) {
#pragma unroll
            for (int j = 0; j < 5; ++j)
                bfn[j] = *(const half8*)(W1p + ((size_t)((wid * 5 + j) * 20 + kc + 1) * 64 + l) * 8);
        }
        half8 a[5];
#pragma unroll
        for (int mf = 0; mf < 5; ++mf)
            a[mf] = *(const half8*)&Hl[(mf * 16 + lr) * 648 + kc * 32 + lq * 8];
#pragma unroll
        for (int j = 0; j < 5; ++j)
#pragma unroll
            for (int mf = 0; mf < 5; ++mf)
                acc[mf][j] = __builtin_amdgcn_mfma_f32_16x16x32_f16(a[mf], bf[j], acc[mf][j], 0, 0, 0);
#pragma unroll
        for (int j = 0; j < 5; ++j) bf[j] = bfn[j];
    }

    __syncthreads();   // all layer-1 reads of Hl done
#pragma unroll
    for (int mf = 0; mf < 5; ++mf)
#pragma unroll
        for (int j = 0; j < 5; ++j) {
            int col = (wid * 5 + j) * 16 + lr;
#pragma unroll
            for (int i = 0; i < 4; ++i) {
                int row = mf * 16 + lq * 4 + i;
                Hl[row * 648 + col] = (_Float16)lrelu(acc[mf][j][i] + b1v[j]);
            }
        }
    __syncthreads();

    // ---- layer 2: 20 frags (5 mf x 4 nf) over 8 waves: f = wid, wid+8, wid+16 ----
    f32x4 acc2[3];
    acc2[0] = (f32x4){0.f, 0.f, 0.f, 0.f};
    acc2[1] = (f32x4){0.f, 0.f, 0.f, 0.f};
    acc2[2] = (f32x4){0.f, 0.f, 0.f, 0.f};

    for (int kc = 0; kc < 20; ++kc) {
#pragma unroll
        for (int ff = 0; ff < 3; ++ff) {
            int f = wid + ff * 8;
            if (f < 20) {
                int mf2 = f >> 2, nf2 = f & 3;
                half8 a = *(const half8*)&Hl[(mf2 * 16 + lr) * 648 + kc * 32 + lq * 8];
                half8 b = *(const half8*)(W2p + ((size_t)(nf2 * 20 + kc) * 64 + l) * 8);
                acc2[ff] = __builtin_amdgcn_mfma_f32_16x16x32_f16(a, b, acc2[ff], 0, 0, 0);
            }
        }
    }

    __syncthreads();   // all layer-2 reads of Hl done
    float* Sb = (float*)Hl;      // reuse as [80][68] f32 bounce
#pragma unroll
    for (int ff = 0; ff < 3; ++ff) {
        int f = wid + ff * 8;
        if (f < 20) {
            int mf2 = f >> 2, nf2 = f & 3;
            float b2v = ub2[nf2 * 16 + lr];
#pragma unroll
            for (int i = 0; i < 4; ++i) {
                int row = mf2 * 16 + lq * 4 + i;
                Sb[row * 68 + nf2 * 16 + lr] = acc2[ff][i] + b2v;
            }
        }
    }
    __syncthreads();

#pragma unroll
    for (int i = 0; i < 3; ++i) {            // hout: 1280 f4-groups
        int idx = tid + i * 512;
        if (idx < 1280) {
            int n_l = idx >> 4, c4 = idx & 15;
            f4 v = *(f4*)&Sb[n_l * 68 + c4 * 4];
            ((f4*)hout)[(size_t)(n0 + n_l) * 16 + c4] = v;
        }
    }
    if (tid < 64) {
        float ps = 0.f, pq = 0.f;
#pragma unroll 4
        for (int n = 0; n < 80; ++n) {
            float v = Sb[n * 68 + tid];
            ps += v; pq += v * v;
        }
        atomicAdd(&bn_acc[tid], ps);
        atomicAdd(&bn_acc[64 + tid], pq);
    }
}

// ---------------- K5: BN finalize (in place on d_out) ----------------
__global__ __launch_bounds__(256) void k5_bnorm(
    const float* __restrict__ bn_acc,
    const float* __restrict__ gamma, const float* __restrict__ beta,
    float* __restrict__ out)
{
    int idx = blockIdx.x * 256 + threadIdx.x;
    int c = idx & 63;
    float mu = bn_acc[c] / (float)N_NODES;
    float var = bn_acc[64 + c] / (float)N_NODES - mu * mu;
    float inv = rsqrtf(var + 1e-5f);
    out[idx] = gamma[c] * (out[idx] - mu) * inv + beta[c];
}

extern "C" void kernel_launch(void* const* d_in, const int* in_sizes, int n_in,
                              void* d_out, int out_size, void* d_ws, size_t ws_size,
                              hipStream_t stream)
{
    const float* x_s = (const float*)d_in[0];
    const float* x_t = (const float*)d_in[1];
    const float* ea  = (const float*)d_in[2];
    const float* x_u = (const float*)d_in[3];
    const float* mW1 = (const float*)d_in[4];
    const float* mb1 = (const float*)d_in[5];
    const float* mW2 = (const float*)d_in[6];
    const float* mb2 = (const float*)d_in[7];
    const float* uW1 = (const float*)d_in[8];
    const float* ub1 = (const float*)d_in[9];
    const float* uW2 = (const float*)d_in[10];
    const float* ub2 = (const float*)d_in[11];
    const float* gam = (const float*)d_in[12];
    const float* bet = (const float*)d_in[13];
    const int* ei    = (const int*)d_in[14];
    const int* src = ei;
    const int* tgt = ei + N_EDGES;

    // ws layout (bytes): cur | bn | slot | msg | MU/SD/SK/KU | W1p W2p W1e W2e | xt16 xs16
    char* base = (char*)d_ws;
    int* cur   = (int*)base;
    float* bn  = (float*)(base + 401408);
    int* slot  = (int*)(base + 401920);
    unsigned short* msg = (unsigned short*)(base + 26001920);
    unsigned short* MU  = (unsigned short*)(base + 230801920);
    unsigned short* SD  = (unsigned short*)(base + 256401920);
    unsigned short* SK  = (unsigned short*)(base + 282001920);
    unsigned short* KU  = (unsigned short*)(base + 307601920);
    _Float16* W1p  = (_Float16*)(base + 333201920);
    _Float16* W2p  = (_Float16*)(base + 334021120);
    _Float16* W1e  = (_Float16*)(base + 334103040);
    _Float16* W2e  = (_Float16*)(base + 334135808);
    _Float16* xt16 = (_Float16*)(base + 334168576);   // 12.8 MB
    _Float16* xs16 = (_Float16*)(base + 346968576);   // 12.8 MB -> ends 359,768,576
    float* out = (float*)d_out;

    hipMemsetAsync(d_ws, 0, 401920, stream);

    k0_pack<<<236, 256, 0, stream>>>(uW1, uW2, mW1, mW2, W1p, W2p, W1e, W2e);
    k_xt<<<12500, 256, 0, stream>>>(x_t, xt16, x_s, xs16);
    k_slot<<<N_EDGES / 256, 256, 0, stream>>>(src, cur, slot);
    k1_mfma<<<N_EDGES / 128, 512, 0, stream>>>(xt16, ea, W1e, mb1, W2e, mb2, tgt, msg);
    k_agg<<<N_NODES / 4, 256, 0, stream>>>(cur, slot, msg, MU, SD, SK, KU);
    k3_mfma<<<N_NODES / 80, 512, 0, stream>>>(xs16, x_u, MU, SD, SK, KU,
                                              W1p, ub1, W2p, ub2, out, bn);
    k5_bnorm<<<(N_NODES * 64) / 256, 256, 0, stream>>>(bn, gam, bet, out);
}